// Round 9
// baseline (92563.556 us; speedup 1.0000x reference)
//
#include <hip/hip_runtime.h>
#include <math.h>

#define NB    2048
#define FIN   32
#define HH    512
#define G4    2048           // 4*H
#define BNE   64
#define OUTD  8
#define SEQL  128
#define LOOK  32
#define TOT   (SEQL + LOOK)
#define TB    8              // samples per workgroup
#define NTHR  1024
#define BK    4              // weight rows per staged chunk (32 KB)

__device__ __forceinline__ float sigf(float v) { return 1.0f / (1.0f + expf(-v)); }

// acc[s] (float2) += state_s * w (float2)
#define MAC2(S, HS)                                    \
  {                                                    \
    a[S].x = fmaf(w.x, (HS), a[S].x);                  \
    a[S].y = fmaf(w.y, (HS), a[S].y);                  \
  }
#define MAC2x8()                                       \
  {                                                    \
    MAC2(0, hA.x); MAC2(1, hA.y); MAC2(2, hA.z); MAC2(3, hA.w); \
    MAC2(4, hB.x); MAC2(5, hB.y); MAC2(6, hB.z); MAC2(7, hB.w); \
  }

// T14 staging: issue global loads early, write to LDS late
#define STAGE_ISSUE(W, CH)                                              \
  { const float4* gp = (const float4*)((W) + (size_t)(CH) * BK * G4);   \
    r0 = gp[t]; r1 = gp[t + NTHR]; }
#define STAGE_WRITE(B)                                                  \
  { ((float4*)&smem[(B) * (BK * G4)])[t] = r0;                          \
    ((float4*)&smem[(B) * (BK * G4)])[t + NTHR] = r1; }

// compute BK rows of the staged chunk; S(k) yields &state[k][0]
#define CHUNK_COMPUTE(SROW)                                             \
  {                                                                     \
    const float* wb = &smem[cur * (BK * G4)];                           \
    _Pragma("unroll")                                                   \
    for (int kk = 0; kk < BK; kk++) {                                   \
      const float2 w  = *(const float2*)&wb[kk * G4 + 2 * t];           \
      const float*  sr = (SROW);                                        \
      const float4 hA = *(const float4*)&sr[0];                         \
      const float4 hB = *(const float4*)&sr[4];                         \
      MAC2x8();                                                         \
    }                                                                   \
  }

__global__ __launch_bounds__(NTHR)
void fused_rnn(const float* __restrict__ x,
               const float* __restrict__ Wih0, const float* __restrict__ Whh0,
               const float* __restrict__ bih0, const float* __restrict__ bhh0,
               const float* __restrict__ Wih1, const float* __restrict__ Whh1,
               const float* __restrict__ bih1, const float* __restrict__ bhh1,
               const float* __restrict__ We,   const float* __restrict__ be,
               const float* __restrict__ Wd,   const float* __restrict__ bd,
               const float* __restrict__ Wf,   const float* __restrict__ bf,
               float* __restrict__ out)
{
  // states transposed [k][sample]: fixed-k access is a wave-uniform float4 broadcast
  __shared__ float sh0[HH][TB], sc0[HH][TB], sh1[HH][TB], sc1[HH][TB];  // 64 KB
  // OVERLAY (time-disjoint): weight double-buffer (2 x BK x 2048) DURING k-loops,
  // gate pre-activations sg[8][2048] AFTER k-loops. Both 64 KB.
  __shared__ float smem[2 * BK * G4];
  __shared__ float sq[2][BNE][TB];   // trits [ae][j][sample], 4 KB
  __shared__ float sx[FIN][TB];      // staged x_t, transposed, 1 KB
  __shared__ float sout[TB][OUTD];   // last dense output (AR feedback)

#define SG(S, C) smem[(S) * G4 + (C)]

  const int t  = threadIdx.x;          // 0..1023
  const int b0 = blockIdx.x * TB;      // first sample of this WG

  for (int i = t; i < HH * TB; i += NTHR) {
    (&sh0[0][0])[i] = 0.f; (&sc0[0][0])[i] = 0.f;
    (&sh1[0][0])[i] = 0.f; (&sc1[0][0])[i] = 0.f;
  }

  // this thread owns gate cols (2t, 2t+1); bias = bih+bhh for those cols
  const float2 bb0 = make_float2(bih0[2*t]   + bhh0[2*t],
                                 bih0[2*t+1] + bhh0[2*t+1]);
  const float2 bb1 = make_float2(bih1[2*t]   + bhh1[2*t],
                                 bih1[2*t+1] + bhh1[2*t+1]);

  const double Athr = 0.5493061443340549;  // atanh(0.5): round(tanh(u)) threshold

  for (int step = 0; step < TOT; ++step) {
    __syncthreads();

    // ---------------- Phase A: encode both AEs (fp64, 1 bottleneck unit/thread) ----
    {
      const int ae = t >> 9, s = (t >> 6) & 7, n = t & 63;
      const float* Sh = ae ? &sh1[0][0] : &sh0[0][0];
      const float* Sc = ae ? &sc1[0][0] : &sc0[0][0];
      double a0 = (double)be[n];
      const float* we0 = We + n;
#pragma unroll 4
      for (int k = 0; k < HH; k++)
        a0 = fma((double)Sh[k * TB + s], (double)we0[(size_t)k * BNE], a0);
      const float* we1 = We + (size_t)HH * BNE + n;
#pragma unroll 4
      for (int k = 0; k < HH; k++)
        a0 = fma((double)Sc[k * TB + s], (double)we1[(size_t)k * BNE], a0);
      sq[ae][n][s] = (a0 > Athr) ? 1.f : ((a0 < -Athr) ? -1.f : 0.f);
    }
    __syncthreads();

    // ---------------- Phase B: decode both AEs (1 col/thread) -> states; stage x_t --
    {
      float aq0[TB], aq1[TB];
      const float bdv = bd[t];
#pragma unroll
      for (int s = 0; s < TB; s++) { aq0[s] = bdv; aq1[s] = bdv; }
      const float* wd = Wd + t;          // col t, row stride 1024
#pragma unroll 2
      for (int j = 0; j < BNE; j++) {
        const float w = wd[(size_t)j * (2 * HH)];
        const float4 qA0 = *(const float4*)&sq[0][j][0];
        const float4 qB0 = *(const float4*)&sq[0][j][4];
        const float4 qA1 = *(const float4*)&sq[1][j][0];
        const float4 qB1 = *(const float4*)&sq[1][j][4];
        aq0[0] = fmaf(qA0.x, w, aq0[0]); aq0[1] = fmaf(qA0.y, w, aq0[1]);
        aq0[2] = fmaf(qA0.z, w, aq0[2]); aq0[3] = fmaf(qA0.w, w, aq0[3]);
        aq0[4] = fmaf(qB0.x, w, aq0[4]); aq0[5] = fmaf(qB0.y, w, aq0[5]);
        aq0[6] = fmaf(qB0.z, w, aq0[6]); aq0[7] = fmaf(qB0.w, w, aq0[7]);
        aq1[0] = fmaf(qA1.x, w, aq1[0]); aq1[1] = fmaf(qA1.y, w, aq1[1]);
        aq1[2] = fmaf(qA1.z, w, aq1[2]); aq1[3] = fmaf(qA1.w, w, aq1[3]);
        aq1[4] = fmaf(qB1.x, w, aq1[4]); aq1[5] = fmaf(qB1.y, w, aq1[5]);
        aq1[6] = fmaf(qB1.z, w, aq1[6]); aq1[7] = fmaf(qB1.w, w, aq1[7]);
      }
      if (t < HH) {
#pragma unroll
        for (int s = 0; s < TB; s++) { sh0[t][s] = aq0[s]; sh1[t][s] = aq1[s]; }
      } else {
        const int c = t - HH;
#pragma unroll
        for (int s = 0; s < TB; s++) { sc0[c][s] = aq0[s]; sc1[c][s] = aq1[s]; }
      }
      if (t < FIN * TB) {   // 256 threads stage x_t (with AR feedback)
        int s = t >> 5, f = t & 31;
        float xv;
        if (step >= SEQL && f < OUTD) xv = sout[s][f];
        else xv = x[((size_t)(b0 + s) * TOT + step) * FIN + f];
        sx[f][s] = xv;
      }
    }
    __syncthreads();

    // ---------------- Phase C: layer-0 matmul (staged weights) ----------------
    {
      float2 a[TB];
#pragma unroll
      for (int s = 0; s < TB; s++) a[s] = bb0;
      float4 r0, r1;
      int cur = 0;
      // prologue: stage Wih0 chunk 0
      STAGE_ISSUE(Wih0, 0);
      STAGE_WRITE(0);
      __syncthreads();
      // Wih0: 8 chunks, chain-prefetch into Whh0
      for (int c = 0; c < FIN / BK; c++) {
        if (c < FIN / BK - 1) STAGE_ISSUE(Wih0, c + 1)
        else                  STAGE_ISSUE(Whh0, 0);
        CHUNK_COMPUTE(&sx[BK * c + kk][0]);
        STAGE_WRITE(cur ^ 1);
        __syncthreads();
        cur ^= 1;
      }
      // Whh0: 128 chunks
      for (int c = 0; c < HH / BK; c++) {
        const bool pf = (c < HH / BK - 1);
        if (pf) STAGE_ISSUE(Whh0, c + 1);
        CHUNK_COMPUTE(&sh0[BK * c + kk][0]);
        if (pf) STAGE_WRITE(cur ^ 1);
        __syncthreads();          // also fences last chunk reads before sg write
        cur ^= 1;
      }
#pragma unroll
      for (int s = 0; s < TB; s++) *(float2*)&SG(s, 2 * t) = a[s];
    }
    __syncthreads();
    // layer-0 elementwise: unit h = t&511, 4 samples per thread
    {
      const int h  = t & (HH - 1);
      const int sb = (t >> 9) * 4;
#pragma unroll
      for (int s2 = 0; s2 < 4; s2++) {
        const int s = sb + s2;
        const float ig = sigf(SG(s, h));
        const float fg = sigf(SG(s, HH + h));
        const float gt = tanhf(SG(s, 2 * HH + h));
        const float og = sigf(SG(s, 3 * HH + h));
        const float c2 = fmaf(fg, sc0[h][s], ig * gt);
        sc0[h][s] = c2;
        sh0[h][s] = og * tanhf(c2);
      }
    }
    __syncthreads();

    // ---------------- Phase D: layer-1 matmul (staged weights) ----------------
    {
      float2 a[TB];
#pragma unroll
      for (int s = 0; s < TB; s++) a[s] = bb1;
      float4 r0, r1;
      int cur = 0;
      // prologue: stage Wih1 chunk 0
      STAGE_ISSUE(Wih1, 0);
      STAGE_WRITE(0);
      __syncthreads();
      // Wih1: 128 chunks (input = new h0), chain-prefetch into Whh1
      for (int c = 0; c < HH / BK; c++) {
        if (c < HH / BK - 1) STAGE_ISSUE(Wih1, c + 1)
        else                 STAGE_ISSUE(Whh1, 0);
        CHUNK_COMPUTE(&sh0[BK * c + kk][0]);
        STAGE_WRITE(cur ^ 1);
        __syncthreads();
        cur ^= 1;
      }
      // Whh1: 128 chunks (recurrent = decoded h1)
      for (int c = 0; c < HH / BK; c++) {
        const bool pf = (c < HH / BK - 1);
        if (pf) STAGE_ISSUE(Whh1, c + 1);
        CHUNK_COMPUTE(&sh1[BK * c + kk][0]);
        if (pf) STAGE_WRITE(cur ^ 1);
        __syncthreads();
        cur ^= 1;
      }
#pragma unroll
      for (int s = 0; s < TB; s++) *(float2*)&SG(s, 2 * t) = a[s];
    }
    __syncthreads();
    // layer-1 elementwise
    {
      const int h  = t & (HH - 1);
      const int sb = (t >> 9) * 4;
#pragma unroll
      for (int s2 = 0; s2 < 4; s2++) {
        const int s = sb + s2;
        const float ig = sigf(SG(s, h));
        const float fg = sigf(SG(s, HH + h));
        const float gt = tanhf(SG(s, 2 * HH + h));
        const float og = sigf(SG(s, 3 * HH + h));
        const float c2 = fmaf(fg, sc1[h][s], ig * gt);
        sc1[h][s] = c2;
        sh1[h][s] = og * tanhf(c2);
      }
    }

    // ---------------- Phase E: final dense (warm-up end + every AR step) ----------
    if (step >= SEQL - 1) {
      __syncthreads();  // new sh1 visible
      if (t < TB * OUTD) {
        int s = t >> 3, o = t & 7;
        float a = bf[o];
#pragma unroll 4
        for (int k = 0; k < HH; k++) a = fmaf(sh1[k][s], Wf[k * OUTD + o], a);
        sout[s][o] = a;
        int slot = step - (SEQL - 1);                 // 0..32
        out[((size_t)(b0 + s) * (1 + LOOK) + slot) * OUTD + o] = a;
      }
    }
  }
#undef SG
}

extern "C" void kernel_launch(void* const* d_in, const int* in_sizes, int n_in,
                              void* d_out, int out_size, void* d_ws, size_t ws_size,
                              hipStream_t stream) {
  const float* x    = (const float*)d_in[0];
  const float* Wih0 = (const float*)d_in[1];
  const float* Whh0 = (const float*)d_in[2];
  const float* bih0 = (const float*)d_in[3];
  const float* bhh0 = (const float*)d_in[4];
  const float* Wih1 = (const float*)d_in[5];
  const float* Whh1 = (const float*)d_in[6];
  const float* bih1 = (const float*)d_in[7];
  const float* bhh1 = (const float*)d_in[8];
  const float* We   = (const float*)d_in[9];
  const float* be   = (const float*)d_in[10];
  const float* Wd   = (const float*)d_in[11];
  const float* bd   = (const float*)d_in[12];
  const float* Wf   = (const float*)d_in[13];
  const float* bf   = (const float*)d_in[14];

  fused_rnn<<<NB / TB, NTHR, 0, stream>>>(x, Wih0, Whh0, bih0, bhh0,
                                          Wih1, Whh1, bih1, bhh1,
                                          We, be, Wd, bd, Wf, bf,
                                          (float*)d_out);
}